// Round 9
// baseline (149.368 us; speedup 1.0000x reference)
//
#include <hip/hip_runtime.h>
#include <math.h>

// Problem shape (fixed by setup_inputs): B=8192 rows, D=2048 cols, fp32.
static constexpr int Dn = 2048;
static constexpr int Bn = 8192;
static constexpr int NBLK  = 1024;       // 256 thr each -> 4096 waves
static constexpr int NWAVE = NBLK * 4;   // 2 rows per wave

typedef float f4 __attribute__((ext_vector_type(4)));

__device__ __forceinline__ float dot4(f4 a, f4 b) {
    return a.x * b.x + a.y * b.y + a.z * b.z + a.w * b.w;
}

// Single fused kernel = R8's k_main + last-block-done finisher.
// R6 tried this fusion and regressed 44-65 us — but rocprof showed VGPR=64:
// the 8-wave/EU register heuristic spilled the 24-f4 live set. R7/R8 proved
// __launch_bounds__(256,4) (cap 128 VGPR) keeps this body un-spilled. The
// fusion itself was always correct; retrying with the cap.
// Per wave:
//  - issue BOTH rows' 8+8 dwordx4 loads first (16 outstanding HBM loads/lane)
//  - anchor kept UNNORMALIZED; its norm butterfly is an independent chain,
//    inv folds into the lane-0 epilogue scale
//  - 5 independent 6-step __shfl_xor butterflies (dual-issue)
// Per block: LDS-reduce 4 wave triples -> one fp64 triple -> part[] (SoA,
//  24 KB). __threadfence + atomicAdd(done); last block re-reduces the L2-hot
//  1024 triples and writes the scalar. One launch total (plus a 4 B memset).
__global__ __launch_bounds__(256, 4) void k_fused(const float* __restrict__ embed,
                                                  const float* __restrict__ ee,
                                                  const float* __restrict__ labels,
                                                  double* __restrict__ part,
                                                  unsigned int* __restrict__ done,
                                                  float* __restrict__ out) {
    __shared__ double bE[4], bL[4], bN[4];
    __shared__ int isLast;
    const int t    = threadIdx.x;
    const int lane = t & 63;
    const int w    = t >> 6;
    const int blk  = blockIdx.x;
    const int wv   = (blk << 2) | w;     // global wave id
    const int j0   = wv;                 // row pair
    const int j1   = wv + NWAVE;

    // ---- both rows' loads issued first: 16 dwordx4 in flight per lane ----
    const f4* r0 = reinterpret_cast<const f4*>(ee + (size_t)j0 * Dn);
    const f4* r1 = reinterpret_cast<const f4*>(ee + (size_t)j1 * Dn);
    f4 x0[8], x1[8];
#pragma unroll
    for (int s = 0; s < 8; ++s) x0[s] = r0[(s << 6) + lane];
#pragma unroll
    for (int s = 0; s < 8; ++s) x1[s] = r1[(s << 6) + lane];

    // labels early too (lane 0 only consumes them)
    float lb0 = 0.f, lb1 = 0.f;
    if (lane == 0) { lb0 = labels[j0]; lb1 = labels[j1]; }

    // ---- raw anchor fragment (L2-hot broadcast; no normalization) ----
    const f4* e0 = reinterpret_cast<const f4*>(embed);
    f4 av[8];
    float ss = 0.f;
#pragma unroll
    for (int s = 0; s < 8; ++s) {
        av[s] = e0[(s << 6) + lane];
        ss += dot4(av[s], av[s]);
    }

    // ---- in-lane dots for both rows (raw anchor) ----
    float dt0 = 0.f, sr0 = 0.f, dt1 = 0.f, sr1 = 0.f;
#pragma unroll
    for (int s = 0; s < 8; ++s) {
        dt0 += dot4(x0[s], av[s]);
        sr0 += dot4(x0[s], x0[s]);
        dt1 += dot4(x1[s], av[s]);
        sr1 += dot4(x1[s], x1[s]);
    }

    // ---- five independent butterfly chains (dual-issue) ----
#pragma unroll
    for (int o = 32; o > 0; o >>= 1) {
        ss  += __shfl_xor(ss,  o, 64);
        dt0 += __shfl_xor(dt0, o, 64);
        dt1 += __shfl_xor(dt1, o, 64);
        sr0 += __shfl_xor(sr0, o, 64);
        sr1 += __shfl_xor(sr1, o, 64);
    }

    // ---- wave triple -> LDS ----
    if (lane == 0) {
        const float nrm = sqrtf(ss);
        const float inv = 1.0f / fmaxf(nrm, 1e-12f);      // F.normalize eps
        const float na  = fmaxf(nrm * inv, 1e-6f);        // = max(||a||,1e-6) ~ 1
        const float sc  = -10.0f * inv / na;              // folds 1/T and inv
        double sE = 0.0, sL = 0.0, sN = 0.0;
        if (j0 != 0) {  // mask: exclude j == i == 0 (j0 == 0 only for wave 0)
            const float neg = sc * dt0 / fmaxf(sqrtf(sr0), 1e-6f);
            sE += (double)expf(neg);
            sL += (double)lb0;
            sN += (double)lb0 * (double)neg;
        }
        {
            const float neg = sc * dt1 / fmaxf(sqrtf(sr1), 1e-6f);
            sE += (double)expf(neg);
            sL += (double)lb1;
            sN += (double)lb1 * (double)neg;
        }
        bE[w] = sE; bL[w] = sL; bN[w] = sN;
    }
    __syncthreads();

    // ---- block triple -> global, then last-block handoff ----
    if (t == 0) {
        part[blk]            = bE[0] + bE[1] + bE[2] + bE[3];
        part[NBLK + blk]     = bL[0] + bL[1] + bL[2] + bL[3];
        part[2 * NBLK + blk] = bN[0] + bN[1] + bN[2] + bN[3];
        __threadfence();                       // release: part[] visible device-wide
        const unsigned int old = atomicAdd(done, 1u);
        isLast = (old == (unsigned int)(NBLK - 1));
    }
    __syncthreads();
    if (!isLast) return;

    // ---- finisher (last block only; 24 KB, L2-hot) ----
    __threadfence();                           // acquire side
    double sE = 0.0, sL = 0.0, sN = 0.0;
    for (int i = t; i < NBLK; i += 256) {
        sE += part[i];
        sL += part[NBLK + i];
        sN += part[2 * NBLK + i];
    }
#pragma unroll
    for (int o = 32; o > 0; o >>= 1) {
        sE += __shfl_down(sE, o, 64);
        sL += __shfl_down(sL, o, 64);
        sN += __shfl_down(sN, o, 64);
    }
    if (lane == 0) { bE[w] = sE; bL[w] = sL; bN[w] = sN; }
    __syncthreads();
    if (t == 0) {
        const double E0 = 1e-12 + bE[0] + bE[1] + bE[2] + bE[3];
        const double S2 = bL[0] + bL[1] + bL[2] + bL[3];
        const double S3 = bN[0] + bN[1] + bN[2] + bN[3];
        const double l0 = (double)labels[0];
        const double C0 = 1e-12 + l0 * S2;
        const double L0 = -(l0 / C0) * (S3 - log(E0) * S2);
        out[0] = (float)(L0 / (double)Bn);
    }
}

extern "C" void kernel_launch(void* const* d_in, const int* in_sizes, int n_in,
                              void* d_out, int out_size, void* d_ws, size_t ws_size,
                              hipStream_t stream) {
    const float* embed  = (const float*)d_in[0];  // [B, D] — only row 0 used
    const float* ee     = (const float*)d_in[1];  // [B, D]
    const float* labels = (const float*)d_in[2];  // [B]
    float* out = (float*)d_out;

    // ws layout: part = 3*NBLK doubles (24 KB), then the 4-byte done counter.
    double* part = (double*)d_ws;
    unsigned int* done = (unsigned int*)((char*)d_ws + 3 * NBLK * sizeof(double));

    // Counter must start at 0 every call (ws is 0xAA-poisoned before timed
    // launches, undefined on the correctness call) — tiny async memset is
    // graph-capturable.
    hipMemsetAsync(done, 0, sizeof(unsigned int), stream);
    k_fused<<<NBLK, 256, 0, stream>>>(embed, ee, labels, part, done, out);
}

// Round 10
// 125.473 us; speedup vs baseline: 1.1904x; 1.1904x over previous
//
#include <hip/hip_runtime.h>
#include <math.h>

// Problem shape (fixed by setup_inputs): B=8192 rows, D=2048 cols, fp32.
static constexpr int Dn = 2048;
static constexpr int Bn = 8192;
static constexpr int NBLK  = 1024;       // 256 thr each -> 4096 waves
static constexpr int NWAVE = NBLK * 4;   // 2 rows per wave

typedef float f4 __attribute__((ext_vector_type(4)));

__device__ __forceinline__ float dot4(f4 a, f4 b) {
    return a.x * b.x + a.y * b.y + a.z * b.z + a.w * b.w;
}

// R8's two-kernel structure (best: 126.2 us) + sched_barrier load pinning.
// Evidence trail: R6/R9 showed the compiler allocates only 52-64 VGPR for
// this body even under __launch_bounds__(256,4) — the bound caps but does
// not force; the scheduler sinks the 24 batched f4 loads into their uses,
// leaving ~6 loads in flight -> latency-bound. __builtin_amdgcn_sched_barrier(0)
// after the load block forbids moving any load below it: all 24 results are
// simultaneously live, forcing ~110 VGPR and a genuinely batched load wave.
// (Last-block fusion measured +25 us twice (R6/R9) — structural cost of the
// per-block agent fence + atomic + serial tail. Permanently rejected.)
__global__ __launch_bounds__(256, 4) void k_main(const float* __restrict__ embed,
                                                 const float* __restrict__ ee,
                                                 const float* __restrict__ labels,
                                                 double* __restrict__ part) {
    __shared__ double bE[4], bL[4], bN[4];
    const int t    = threadIdx.x;
    const int lane = t & 63;
    const int w    = t >> 6;
    const int wv   = ((int)blockIdx.x << 2) | w;  // global wave id
    const int j0   = wv;                          // row pair
    const int j1   = wv + NWAVE;

    // ---- ALL loads issued first: 16 row + 8 anchor dwordx4 per lane ----
    const f4* r0 = reinterpret_cast<const f4*>(ee + (size_t)j0 * Dn);
    const f4* r1 = reinterpret_cast<const f4*>(ee + (size_t)j1 * Dn);
    const f4* e0 = reinterpret_cast<const f4*>(embed);
    f4 x0[8], x1[8], av[8];
#pragma unroll
    for (int s = 0; s < 8; ++s) x0[s] = r0[(s << 6) + lane];
#pragma unroll
    for (int s = 0; s < 8; ++s) x1[s] = r1[(s << 6) + lane];
#pragma unroll
    for (int s = 0; s < 8; ++s) av[s] = e0[(s << 6) + lane];

    // labels early too (lane 0 only consumes them)
    float lb0 = 0.f, lb1 = 0.f;
    if (lane == 0) { lb0 = labels[j0]; lb1 = labels[j1]; }

    // Pin: no load may be scheduled below this point -> 24 f4 results live.
    __builtin_amdgcn_sched_barrier(0);

    // ---- in-lane dots (raw, unnormalized anchor) ----
    float ss = 0.f, dt0 = 0.f, sr0 = 0.f, dt1 = 0.f, sr1 = 0.f;
#pragma unroll
    for (int s = 0; s < 8; ++s) {
        ss  += dot4(av[s], av[s]);
        dt0 += dot4(x0[s], av[s]);
        sr0 += dot4(x0[s], x0[s]);
        dt1 += dot4(x1[s], av[s]);
        sr1 += dot4(x1[s], x1[s]);
    }

    // ---- five independent butterfly chains (dual-issue) ----
#pragma unroll
    for (int o = 32; o > 0; o >>= 1) {
        ss  += __shfl_xor(ss,  o, 64);
        dt0 += __shfl_xor(dt0, o, 64);
        dt1 += __shfl_xor(dt1, o, 64);
        sr0 += __shfl_xor(sr0, o, 64);
        sr1 += __shfl_xor(sr1, o, 64);
    }

    // ---- wave triple -> LDS ----
    if (lane == 0) {
        const float nrm = sqrtf(ss);
        const float inv = 1.0f / fmaxf(nrm, 1e-12f);      // F.normalize eps
        const float na  = fmaxf(nrm * inv, 1e-6f);        // = max(||a||,1e-6) ~ 1
        const float sc  = -10.0f * inv / na;              // folds 1/T and inv
        double sE = 0.0, sL = 0.0, sN = 0.0;
        if (j0 != 0) {  // mask: exclude j == i == 0 (j0 == 0 only for wave 0)
            const float neg = sc * dt0 / fmaxf(sqrtf(sr0), 1e-6f);
            sE += (double)expf(neg);
            sL += (double)lb0;
            sN += (double)lb0 * (double)neg;
        }
        {
            const float neg = sc * dt1 / fmaxf(sqrtf(sr1), 1e-6f);
            sE += (double)expf(neg);
            sL += (double)lb1;
            sN += (double)lb1 * (double)neg;
        }
        bE[w] = sE; bL[w] = sL; bN[w] = sN;
    }
    __syncthreads();

    // ---- block triple -> global (SoA; 24 KB total) ----
    if (t == 0) {
        part[blockIdx.x]            = bE[0] + bE[1] + bE[2] + bE[3];
        part[NBLK + blockIdx.x]     = bL[0] + bL[1] + bL[2] + bL[3];
        part[2 * NBLK + blockIdx.x] = bN[0] + bN[1] + bN[2] + bN[3];
    }
}

// Finisher: 1 block, fp64 reduce of 1024 block-partials (24 KB, L2-hot):
//   E0 = 1e-12 + SE;  C0 = 1e-12 + l0*SL
//   L0 = -(l0/C0) * (SN - log(E0)*SL);  out = L0/B
__global__ __launch_bounds__(256) void k_final(const double* __restrict__ part,
                                               const float* __restrict__ labels,
                                               float* __restrict__ out) {
    __shared__ double rE[4], rL[4], rN[4];
    const int t = threadIdx.x;
    const int lane = t & 63, wave = t >> 6;

    double sE = 0.0, sL = 0.0, sN = 0.0;
    for (int i = t; i < NBLK; i += 256) {
        sE += part[i];
        sL += part[NBLK + i];
        sN += part[2 * NBLK + i];
    }
#pragma unroll
    for (int o = 32; o > 0; o >>= 1) {
        sE += __shfl_down(sE, o, 64);
        sL += __shfl_down(sL, o, 64);
        sN += __shfl_down(sN, o, 64);
    }
    if (lane == 0) { rE[wave] = sE; rL[wave] = sL; rN[wave] = sN; }
    __syncthreads();
    if (t == 0) {
        const double E0 = 1e-12 + rE[0] + rE[1] + rE[2] + rE[3];
        const double S2 = rL[0] + rL[1] + rL[2] + rL[3];
        const double S3 = rN[0] + rN[1] + rN[2] + rN[3];
        const double l0 = (double)labels[0];
        const double C0 = 1e-12 + l0 * S2;
        const double L0 = -(l0 / C0) * (S3 - log(E0) * S2);
        out[0] = (float)(L0 / (double)Bn);
    }
}

extern "C" void kernel_launch(void* const* d_in, const int* in_sizes, int n_in,
                              void* d_out, int out_size, void* d_ws, size_t ws_size,
                              hipStream_t stream) {
    const float* embed  = (const float*)d_in[0];  // [B, D] — only row 0 used
    const float* ee     = (const float*)d_in[1];  // [B, D]
    const float* labels = (const float*)d_in[2];  // [B]
    float* out = (float*)d_out;

    double* part = (double*)d_ws;  // 3 * NBLK doubles = 24 KB, fully overwritten

    k_main<<<NBLK, 256, 0, stream>>>(embed, ee, labels, part);
    k_final<<<1, 256, 0, stream>>>(part, labels, out);
}